// Round 8
// baseline (517.589 us; speedup 1.0000x reference)
//
#include <hip/hip_runtime.h>
#include <hip/hip_bf16.h>

// Problem constants
#define B_ 4
#define DIM_ 256
#define N_ 2048
#define M_ 2048
#define HEADS_ 8
#define DHEAD_ 64
#define DINNER_ 512

typedef __attribute__((ext_vector_type(8))) short short8;
typedef __attribute__((ext_vector_type(4))) short short4v;
typedef __attribute__((ext_vector_type(4))) float floatx4;
typedef __attribute__((ext_vector_type(4))) _Float16 half4;

__device__ inline short bf16r(float x) {  // RNE f32->bf16 (bit form)
  unsigned u = __float_as_uint(x);
  unsigned r = (u + 0x7fffu + ((u >> 16) & 1u)) >> 16;
  return (short)r;
}
__device__ inline float bf2f(short b) {
  return __uint_as_float(((unsigned)(unsigned short)b) << 16);
}

// ---------------------------------------------------------------------------
// Kernel 0: one-shot W split: whi/wlo bf16 planes of (W * gamma).
// ---------------------------------------------------------------------------
__global__ __launch_bounds__(256) void wsplit_kernel(
    const float* __restrict__ Wq, const float* __restrict__ Wkv,
    const float* __restrict__ Wout, const float* __restrict__ gamma,
    const float* __restrict__ gctx, short* __restrict__ whi,
    short* __restrict__ wlo) {
  const int y = blockIdx.y;
  const int gsz[3] = {32768, 65536, 32768};  // float4 groups per matrix
  const int goff[3] = {0, 131072, 393216};   // element offset in planes
  int gidx = blockIdx.x * 256 + threadIdx.x;
  if (gidx >= gsz[y]) return;
  const float* W = (y == 0) ? Wq : (y == 1) ? Wkv : Wout;
  const int cmask = (y == 2) ? 511 : 255;
  int e0 = gidx * 4;
  int c = e0 & cmask;
  float4 wv = *(const float4*)&W[e0];
  if (y < 2) {
    const float* g = (y == 0) ? gamma : gctx;
    float4 g4 = *(const float4*)&g[c];
    wv.x *= g4.x; wv.y *= g4.y; wv.z *= g4.z; wv.w *= g4.w;
  }
  float vv[4] = {wv.x, wv.y, wv.z, wv.w};
  short4v hi, lo;
#pragma unroll
  for (int e = 0; e < 4; ++e) {
    short hb = bf16r(vv[e]);
    hi[e] = hb;
    lo[e] = bf16r(vv[e] - bf2f(hb));
  }
  *(short4v*)&whi[goff[y] + e0] = hi;
  *(short4v*)&wlo[goff[y] + e0] = lo;
}

// ---------------------------------------------------------------------------
// Kernel 1: channel RMSNorm -> bf16 transposed, coalesced via LDS transpose.
// ---------------------------------------------------------------------------
__global__ __launch_bounds__(256) void colnorm_t_kernel(
    const float* __restrict__ x, short* __restrict__ xt, int NN) {
  int b = blockIdx.y;
  int tx = threadIdx.x, ty = threadIdx.y;
  int n0 = blockIdx.x * 64, n = n0 + tx;
  const float* xb = x + (size_t)b * 256 * NN;

  float ssq = 0.f;
  for (int c = ty; c < 256; c += 4) {
    float v = xb[(size_t)c * NN + n];
    ssq += v * v;
  }
  __shared__ float red[4][64];
  __shared__ float scl[64];
  __shared__ float t[64][65];
  red[ty][tx] = ssq;
  __syncthreads();
  if (ty == 0) {
    float s = red[0][tx] + red[1][tx] + red[2][tx] + red[3][tx];
    scl[tx] = 16.0f / fmaxf(sqrtf(s), 1e-12f);
  }
  int tid = ty * 64 + tx;
  int row = tid >> 2, cg = tid & 3;
  for (int c0 = 0; c0 < 256; c0 += 64) {
    __syncthreads();
    for (int cc = ty; cc < 64; cc += 4) t[cc][tx] = xb[(size_t)(c0 + cc) * NN + n];
    __syncthreads();
    float sc = scl[row];
    short8 o0v, o1v;
#pragma unroll
    for (int e = 0; e < 8; ++e) {
      o0v[e] = bf16r(t[cg * 16 + e][row] * sc);
      o1v[e] = bf16r(t[cg * 16 + 8 + e][row] * sc);
    }
    size_t base = ((size_t)b * NN + n0 + row) * 256 + c0 + cg * 16;
    *(short8*)&xt[base] = o0v;
    *(short8*)&xt[base + 8] = o1v;
  }
}

// ---------------------------------------------------------------------------
// Kernel 2: MFMA GEMM from pre-split bf16 W planes.
// EPI: 0 = fp32 out-proj, 1 = bf16 [b][n][512] (q), 2 = kv: K->EPI1, V->f16
// [b][ch][m] (f16 for the 16x16x16f16 PV MFMA; more mantissa than bf16).
// ---------------------------------------------------------------------------
template <int EPI>
__global__ __launch_bounds__(256) void gemm_mfma_kernel(
    const short* __restrict__ whi, const short* __restrict__ wlo,
    const short* __restrict__ Xt, float* __restrict__ Yf,
    short* __restrict__ Yt, _Float16* __restrict__ Yv, int C, int O) {
  const int b = blockIdx.z;
  const int n0 = blockIdx.x * 128;
  const int o0 = blockIdx.y * 128;
  const int tid = threadIdx.x;
  const int w = tid >> 6, l = tid & 63, quad = l >> 4, l15 = l & 15;
  const int wo = (w >> 1) * 64, wn = (w & 1) * 64;

  __shared__ __align__(16) short Wa[2][128][40];
  __shared__ __align__(16) short Xb[128][40];

  floatx4 acc[4][4];
#pragma unroll
  for (int ot = 0; ot < 4; ++ot)
#pragma unroll
    for (int nt = 0; nt < 4; ++nt)
#pragma unroll
      for (int r = 0; r < 4; ++r) acc[ot][nt][r] = 0.f;

  for (int c0 = 0; c0 < C; c0 += 32) {
    __syncthreads();
#pragma unroll
    for (int it = 0; it < 2; ++it) {
      int lin = tid + it * 256;
      int row = lin >> 2, sg = (lin & 3) * 8;
      size_t src = (size_t)(o0 + row) * C + c0 + sg;
      *(short8*)&Wa[0][row][sg] = *(const short8*)&whi[src];
      *(short8*)&Wa[1][row][sg] = *(const short8*)&wlo[src];
    }
#pragma unroll
    for (int it = 0; it < 2; ++it) {
      int lin = tid + it * 256;
      int nn = lin >> 2, sg = (lin & 3) * 8;
      *(short8*)&Xb[nn][sg] =
          *(const short8*)&Xt[((size_t)b * 2048 + n0 + nn) * C + c0 + sg];
    }
    __syncthreads();

    short8 ah[4], al[4], bx[4];
#pragma unroll
    for (int ot = 0; ot < 4; ++ot) {
      ah[ot] = *(const short8*)&Wa[0][wo + 16 * ot + l15][8 * quad];
      al[ot] = *(const short8*)&Wa[1][wo + 16 * ot + l15][8 * quad];
    }
#pragma unroll
    for (int nt = 0; nt < 4; ++nt)
      bx[nt] = *(const short8*)&Xb[wn + 16 * nt + l15][8 * quad];
#pragma unroll
    for (int ot = 0; ot < 4; ++ot)
#pragma unroll
      for (int nt = 0; nt < 4; ++nt) {
        acc[ot][nt] =
            __builtin_amdgcn_mfma_f32_16x16x32_bf16(al[ot], bx[nt], acc[ot][nt], 0, 0, 0);
        acc[ot][nt] =
            __builtin_amdgcn_mfma_f32_16x16x32_bf16(ah[ot], bx[nt], acc[ot][nt], 0, 0, 0);
      }
  }

  if (EPI == 0) {
#pragma unroll
    for (int ot = 0; ot < 4; ++ot)
#pragma unroll
      for (int r = 0; r < 4; ++r) {
        int o = o0 + wo + 16 * ot + 4 * quad + r;
#pragma unroll
        for (int nt = 0; nt < 4; ++nt)
          Yf[((size_t)b * O + o) * 2048 + n0 + wn + 16 * nt + l15] =
              acc[ot][nt][r];
      }
  } else if (EPI == 1 || (EPI == 2 && o0 < 512)) {
#pragma unroll
    for (int nt = 0; nt < 4; ++nt) {
      int n = n0 + wn + 16 * nt + l15;
      size_t base = ((size_t)b * 2048 + n) * 512;
#pragma unroll
      for (int ot = 0; ot < 4; ++ot) {
        int o = o0 + wo + 16 * ot + 4 * quad;
        short4v pk;
#pragma unroll
        for (int r = 0; r < 4; ++r) pk[r] = bf16r(acc[ot][nt][r]);
        *(short4v*)&Yt[base + o] = pk;
      }
    }
  } else {
#pragma unroll
    for (int ot = 0; ot < 4; ++ot)
#pragma unroll
      for (int r = 0; r < 4; ++r) {
        int ch = o0 - 512 + wo + 16 * ot + 4 * quad + r;
#pragma unroll
        for (int nt = 0; nt < 4; ++nt)
          Yv[((size_t)b * 512 + ch) * 2048 + n0 + wn + 16 * nt + l15] =
              (_Float16)acc[ot][nt][r];
      }
  }
}

// ---------------------------------------------------------------------------
// Kernel 3: k2m[(b*8+h)*M+m] = mask ? sum_d k~[m][h*64+d]^2 : +INF
// ---------------------------------------------------------------------------
__global__ __launch_bounds__(256) void k2_kernel(const short* __restrict__ kbT,
                                                 const int* __restrict__ mask,
                                                 float* __restrict__ k2m) {
  int w = threadIdx.x >> 6, l = threadIdx.x & 63;
  int row = blockIdx.x * 4 + w;  // row in [0, B*M)
  int b = row >> 11, m = row & 2047;
  short8 v = *(const short8*)&kbT[(size_t)row * 512 + 8 * l];
  float s = 0.f;
#pragma unroll
  for (int e = 0; e < 8; ++e) {
    float f = bf2f(v[e]);
    s += f * f;
  }
  s += __shfl_xor(s, 1);
  s += __shfl_xor(s, 2);
  s += __shfl_xor(s, 4);
  int mv = mask[row];
  if ((l & 7) == 0) {
    int h = l >> 3;
    k2m[((size_t)b * 8 + h) * 2048 + m] = mv ? s : __builtin_inff();
  }
}

// ---------------------------------------------------------------------------
// Kernel 4: L2-distance flash attention, S^T formulation — NO LDS in j-loop.
// S^T = K*Q^T (A=K rows j, B=Q^T cols i).  C-layout of S^T is
// (j=4*quad+r, i=l15), which IS the B-fragment layout of
// mfma_f32_16x16x16_f16 (k=4*quad+jj, n=l15): softmaxed P feeds PV directly
// from registers.  PV: A = V^T f16 fragments (m=d=l15, k=j=4*quad+jj),
// accumulating O^T.  q2: lane-constant scalar; k2: one coalesced b32 load
// per chunk + shfl distribute; mask folded into k2m (+inf).
// Block 256 = 4 waves: jh=w&1 j-half, iw=w>>1 i-subtile; 32 q-rows/block.
// Grid 2048, XCD-swizzled.  Combine halves = plain add (max==0 softmax).
// ---------------------------------------------------------------------------
__global__ __launch_bounds__(256, 4) void attn_kernel(
    const short* __restrict__ qb, const short* __restrict__ kbT,
    const _Float16* __restrict__ vb, const float* __restrict__ k2m,
    short* __restrict__ attn_t) {
  const int bid = blockIdx.x;
  const int rr = bid & 7, qq = bid >> 3;       // rr ~ XCD
  const int iblk = qq >> 2;                    // [0,64)
  const int g = rr * 4 + (qq & 3);             // bh in [0,32)
  const int h = g & 7, b = g >> 3;
  const int i0 = iblk * 32;

  const int tid = threadIdx.x;
  const int w = tid >> 6, l = tid & 63, quad = l >> 4, l15 = l & 15;
  const int jh = w & 1, iw = w >> 1;

  __shared__ float o_lds[64][34];  // [d][i_local], pad 34 (2-way = free)
  __shared__ float l_lds[32];

  const short* qrow = qb + ((size_t)b * N_ + i0 + 16 * iw + l15) * 512 + h * 64;
  const short* kbase = kbT + (size_t)b * M_ * 512 + h * 64;
  const _Float16* vbase = vb + ((size_t)b * 512 + h * 64) * (size_t)M_;
  const float* k2b = k2m + ((size_t)b * 8 + h) * M_;

  // Q^T B-fragments (n=i=l15, k=d=8*quad+jj) + q2 (per-lane scalar)
  short8 qa0 = *(const short8*)&qrow[8 * quad];
  short8 qa1 = *(const short8*)&qrow[32 + 8 * quad];
  float q2p = 0.f;
#pragma unroll
  for (int jj = 0; jj < 8; ++jj) {
    float f0 = bf2f(qa0[jj]), f1 = bf2f(qa1[jj]);
    q2p += f0 * f0 + f1 * f1;
  }
  q2p += __shfl_xor(q2p, 16);
  q2p += __shfl_xor(q2p, 32);
  const float q2c = q2p;  // q2 for column i=l15, all lanes

  floatx4 accO[4];  // O^T C-layout: (d = 16*dt+4*quad+r, i = l15)
#pragma unroll
  for (int dt = 0; dt < 4; ++dt)
#pragma unroll
    for (int r = 0; r < 4; ++r) accO[dt][r] = 0.f;
  float lsum = 0.f;  // partial l for column i=l15 (this lane's j's)

  const int jbeg = jh * 1024;
  const float C2 = -0.18033688011112042f;  // -0.125 * log2(e)

  for (int j0 = jbeg; j0 < jbeg + 1024; j0 += 64) {
    float k2c = k2b[j0 + l];  // lane l holds k2m[j0+l] (coalesced)

    half4 pb[4];  // P B-fragments per 16-j tile
#pragma unroll
    for (int jt = 0; jt < 4; ++jt) {
      const short* krow = kbase + (size_t)(j0 + 16 * jt + l15) * 512;
      short8 k0 = *(const short8*)&krow[8 * quad];
      short8 k1 = *(const short8*)&krow[32 + 8 * quad];
      floatx4 a;
#pragma unroll
      for (int r = 0; r < 4; ++r) a[r] = 0.f;
      // S^T: A = K (m=j), B = Q^T (n=i)
      a = __builtin_amdgcn_mfma_f32_16x16x32_bf16(k0, qa0, a, 0, 0, 0);
      a = __builtin_amdgcn_mfma_f32_16x16x32_bf16(k1, qa1, a, 0, 0, 0);
#pragma unroll
      for (int r = 0; r < 4; ++r) {
        float k2v = __shfl(k2c, 16 * jt + 4 * quad + r);
        float d2 = fmaxf(fmaf(-2.f, a[r], q2c + k2v), 1e-12f);
        float p = __builtin_amdgcn_exp2f(C2 * __builtin_amdgcn_sqrtf(d2));
        lsum += p;             // RNE f16 rounding below is zero-mean
        pb[jt][r] = (_Float16)p;
      }
    }

    // ---- O^T += V^T P^T, all-register operands ----
#pragma unroll
    for (int dt = 0; dt < 4; ++dt) {
      const _Float16* vrow =
          vbase + (size_t)(16 * dt + l15) * M_ + j0 + 4 * quad;
#pragma unroll
      for (int jt = 0; jt < 4; ++jt) {
        half4 va = *(const half4*)&vrow[16 * jt];
        accO[dt] =
            __builtin_amdgcn_mfma_f32_16x16x16f16(va, pb[jt], accO[dt], 0, 0, 0);
      }
    }
  }

  // total l for column i=l15
  lsum += __shfl_xor(lsum, 16);
  lsum += __shfl_xor(lsum, 32);

  // ---- combine the two j-halves (plain add; max==0 softmax) ----
  if (jh == 1) {
#pragma unroll
    for (int dt = 0; dt < 4; ++dt)
#pragma unroll
      for (int r = 0; r < 4; ++r)
        o_lds[16 * dt + 4 * quad + r][16 * iw + l15] = accO[dt][r];
    if (quad == 0) l_lds[16 * iw + l15] = lsum;
  }
  __syncthreads();
  if (jh == 0) {
    float rl = 1.0f / (lsum + l_lds[16 * iw + l15]);
    size_t base = ((size_t)b * N_ + i0 + 16 * iw + l15) * 512 + h * 64;
#pragma unroll
    for (int dt = 0; dt < 4; ++dt)
#pragma unroll
      for (int r = 0; r < 4; ++r) {
        int d = 16 * dt + 4 * quad + r;
        float o = accO[dt][r] + o_lds[d][16 * iw + l15];
        attn_t[base + d] = bf16r(o * rl);
      }
  }
}

// ---------------------------------------------------------------------------
extern "C" void kernel_launch(void* const* d_in, const int* in_sizes, int n_in,
                              void* d_out, int out_size, void* d_ws,
                              size_t ws_size, hipStream_t stream) {
  const float* fmap = (const float*)d_in[0];
  const float* context = (const float*)d_in[1];
  const int* mask = (const int*)d_in[2];
  const float* gamma = (const float*)d_in[3];
  const float* gamma_ctx = (const float*)d_in[4];
  const float* Wq = (const float*)d_in[5];
  const float* Wkv = (const float*)d_in[6];
  const float* Wout = (const float*)d_in[7];
  float* out = (float*)d_out;

  char* ws = (char*)d_ws;
  short* fmap_t = (short*)ws;                 // 4 MB
  short* ctx_t = fmap_t + 2097152;            // 4 MB
  short* qb = ctx_t + 2097152;                // 8 MB
  short* kbT = qb + 4194304;                  // 8 MB
  _Float16* vb = (_Float16*)(kbT + 4194304);  // 8 MB
  short* attn_t = (short*)(vb + 4194304);     // 8 MB
  float* k2m = (float*)(attn_t + 4194304);    // 256 KB
  short* whi = (short*)(k2m + 65536);         // 1 MB
  short* wlo = whi + 524288;                  // 1 MB

  dim3 blk64x4(64, 4);
  wsplit_kernel<<<dim3(256, 3), 256, 0, stream>>>(Wq, Wkv, Wout, gamma,
                                                  gamma_ctx, whi, wlo);
  colnorm_t_kernel<<<dim3(N_ / 64, B_), blk64x4, 0, stream>>>(fmap, fmap_t, N_);
  colnorm_t_kernel<<<dim3(M_ / 64, B_), blk64x4, 0, stream>>>(context, ctx_t,
                                                              M_);
  gemm_mfma_kernel<1><<<dim3(16, 4, B_), 256, 0, stream>>>(
      whi, wlo, fmap_t, nullptr, qb, nullptr, DIM_, DINNER_);
  gemm_mfma_kernel<2><<<dim3(16, 8, B_), 256, 0, stream>>>(
      whi + 131072, wlo + 131072, ctx_t, nullptr, kbT, vb, DIM_, 2 * DINNER_);
  k2_kernel<<<dim3(B_ * M_ / 4), 256, 0, stream>>>(kbT, mask, k2m);
  attn_kernel<<<dim3(2048), 256, 0, stream>>>(qb, kbT, vb, k2m, attn_t);
  gemm_mfma_kernel<0><<<dim3(16, 2, B_), 256, 0, stream>>>(
      whi + 393216, wlo + 393216, attn_t, out, nullptr, nullptr, DINNER_,
      DIM_);
}

// Round 9
// 421.980 us; speedup vs baseline: 1.2266x; 1.2266x over previous
//
#include <hip/hip_runtime.h>
#include <hip/hip_bf16.h>

// Problem constants
#define B_ 4
#define DIM_ 256
#define N_ 2048
#define M_ 2048
#define HEADS_ 8
#define DHEAD_ 64
#define DINNER_ 512

typedef __attribute__((ext_vector_type(8))) short short8;
typedef __attribute__((ext_vector_type(4))) short short4v;
typedef __attribute__((ext_vector_type(4))) float floatx4;
typedef __attribute__((ext_vector_type(4))) _Float16 half4;
typedef __attribute__((ext_vector_type(8))) _Float16 half8;

__device__ inline short bf16r(float x) {  // RNE f32->bf16 (bit form)
  unsigned u = __float_as_uint(x);
  unsigned r = (u + 0x7fffu + ((u >> 16) & 1u)) >> 16;
  return (short)r;
}
__device__ inline float bf2f(short b) {
  return __uint_as_float(((unsigned)(unsigned short)b) << 16);
}

// ---------------------------------------------------------------------------
// Kernel 0: one-shot W split: whi/wlo bf16 planes of (W * gamma).
// ---------------------------------------------------------------------------
__global__ __launch_bounds__(256) void wsplit_kernel(
    const float* __restrict__ Wq, const float* __restrict__ Wkv,
    const float* __restrict__ Wout, const float* __restrict__ gamma,
    const float* __restrict__ gctx, short* __restrict__ whi,
    short* __restrict__ wlo) {
  const int y = blockIdx.y;
  const int gsz[3] = {32768, 65536, 32768};  // float4 groups per matrix
  const int goff[3] = {0, 131072, 393216};   // element offset in planes
  int gidx = blockIdx.x * 256 + threadIdx.x;
  if (gidx >= gsz[y]) return;
  const float* W = (y == 0) ? Wq : (y == 1) ? Wkv : Wout;
  const int cmask = (y == 2) ? 511 : 255;
  int e0 = gidx * 4;
  int c = e0 & cmask;
  float4 wv = *(const float4*)&W[e0];
  if (y < 2) {
    const float* g = (y == 0) ? gamma : gctx;
    float4 g4 = *(const float4*)&g[c];
    wv.x *= g4.x; wv.y *= g4.y; wv.z *= g4.z; wv.w *= g4.w;
  }
  float vv[4] = {wv.x, wv.y, wv.z, wv.w};
  short4v hi, lo;
#pragma unroll
  for (int e = 0; e < 4; ++e) {
    short hb = bf16r(vv[e]);
    hi[e] = hb;
    lo[e] = bf16r(vv[e] - bf2f(hb));
  }
  *(short4v*)&whi[goff[y] + e0] = hi;
  *(short4v*)&wlo[goff[y] + e0] = lo;
}

// ---------------------------------------------------------------------------
// Kernel 1: channel RMSNorm -> bf16 transposed, coalesced via LDS transpose.
// ---------------------------------------------------------------------------
__global__ __launch_bounds__(256) void colnorm_t_kernel(
    const float* __restrict__ x, short* __restrict__ xt, int NN) {
  int b = blockIdx.y;
  int tx = threadIdx.x, ty = threadIdx.y;
  int n0 = blockIdx.x * 64, n = n0 + tx;
  const float* xb = x + (size_t)b * 256 * NN;

  float ssq = 0.f;
  for (int c = ty; c < 256; c += 4) {
    float v = xb[(size_t)c * NN + n];
    ssq += v * v;
  }
  __shared__ float red[4][64];
  __shared__ float scl[64];
  __shared__ float t[64][65];
  red[ty][tx] = ssq;
  __syncthreads();
  if (ty == 0) {
    float s = red[0][tx] + red[1][tx] + red[2][tx] + red[3][tx];
    scl[tx] = 16.0f / fmaxf(sqrtf(s), 1e-12f);
  }
  int tid = ty * 64 + tx;
  int row = tid >> 2, cg = tid & 3;
  for (int c0 = 0; c0 < 256; c0 += 64) {
    __syncthreads();
    for (int cc = ty; cc < 64; cc += 4) t[cc][tx] = xb[(size_t)(c0 + cc) * NN + n];
    __syncthreads();
    float sc = scl[row];
    short8 o0v, o1v;
#pragma unroll
    for (int e = 0; e < 8; ++e) {
      o0v[e] = bf16r(t[cg * 16 + e][row] * sc);
      o1v[e] = bf16r(t[cg * 16 + 8 + e][row] * sc);
    }
    size_t base = ((size_t)b * NN + n0 + row) * 256 + c0 + cg * 16;
    *(short8*)&xt[base] = o0v;
    *(short8*)&xt[base + 8] = o1v;
  }
}

// ---------------------------------------------------------------------------
// Kernel 2: MFMA GEMM from pre-split bf16 W planes.
// EPI: 0 = fp32 out-proj; 1 = bf16 [b][n][512] (q);
//      2 = kv: K rows (o<512) -> bf16 [b][m][512] scaled by -2 (QK MFMA then
//          accumulates -2qk directly), V rows -> f16 [b][ch][m'] where m' is
//          a within-32 bit-permute (slot q*8+t*4+jj <- j=16t+4q+jj) so the
//          attention kernel's half8 A-fragment loads are contiguous 16B.
// ---------------------------------------------------------------------------
template <int EPI>
__global__ __launch_bounds__(256) void gemm_mfma_kernel(
    const short* __restrict__ whi, const short* __restrict__ wlo,
    const short* __restrict__ Xt, float* __restrict__ Yf,
    short* __restrict__ Yt, _Float16* __restrict__ Yv, int C, int O) {
  const int b = blockIdx.z;
  const int n0 = blockIdx.x * 128;
  const int o0 = blockIdx.y * 128;
  const int tid = threadIdx.x;
  const int w = tid >> 6, l = tid & 63, quad = l >> 4, l15 = l & 15;
  const int wo = (w >> 1) * 64, wn = (w & 1) * 64;

  __shared__ __align__(16) short Wa[2][128][40];
  __shared__ __align__(16) short Xb[128][40];

  floatx4 acc[4][4];
#pragma unroll
  for (int ot = 0; ot < 4; ++ot)
#pragma unroll
    for (int nt = 0; nt < 4; ++nt)
#pragma unroll
      for (int r = 0; r < 4; ++r) acc[ot][nt][r] = 0.f;

  for (int c0 = 0; c0 < C; c0 += 32) {
    __syncthreads();
#pragma unroll
    for (int it = 0; it < 2; ++it) {
      int lin = tid + it * 256;
      int row = lin >> 2, sg = (lin & 3) * 8;
      size_t src = (size_t)(o0 + row) * C + c0 + sg;
      *(short8*)&Wa[0][row][sg] = *(const short8*)&whi[src];
      *(short8*)&Wa[1][row][sg] = *(const short8*)&wlo[src];
    }
#pragma unroll
    for (int it = 0; it < 2; ++it) {
      int lin = tid + it * 256;
      int nn = lin >> 2, sg = (lin & 3) * 8;
      *(short8*)&Xb[nn][sg] =
          *(const short8*)&Xt[((size_t)b * 2048 + n0 + nn) * C + c0 + sg];
    }
    __syncthreads();

    short8 ah[4], al[4], bx[4];
#pragma unroll
    for (int ot = 0; ot < 4; ++ot) {
      ah[ot] = *(const short8*)&Wa[0][wo + 16 * ot + l15][8 * quad];
      al[ot] = *(const short8*)&Wa[1][wo + 16 * ot + l15][8 * quad];
    }
#pragma unroll
    for (int nt = 0; nt < 4; ++nt)
      bx[nt] = *(const short8*)&Xb[wn + 16 * nt + l15][8 * quad];
#pragma unroll
    for (int ot = 0; ot < 4; ++ot)
#pragma unroll
      for (int nt = 0; nt < 4; ++nt) {
        acc[ot][nt] =
            __builtin_amdgcn_mfma_f32_16x16x32_bf16(al[ot], bx[nt], acc[ot][nt], 0, 0, 0);
        acc[ot][nt] =
            __builtin_amdgcn_mfma_f32_16x16x32_bf16(ah[ot], bx[nt], acc[ot][nt], 0, 0, 0);
      }
  }

  if (EPI == 0) {
#pragma unroll
    for (int ot = 0; ot < 4; ++ot)
#pragma unroll
      for (int r = 0; r < 4; ++r) {
        int o = o0 + wo + 16 * ot + 4 * quad + r;
#pragma unroll
        for (int nt = 0; nt < 4; ++nt)
          Yf[((size_t)b * O + o) * 2048 + n0 + wn + 16 * nt + l15] =
              acc[ot][nt][r];
      }
  } else if (EPI == 1 || (EPI == 2 && o0 < 512)) {
    const float kscale = (EPI == 2) ? -2.0f : 1.0f;  // exact pow2 scale
#pragma unroll
    for (int nt = 0; nt < 4; ++nt) {
      int n = n0 + wn + 16 * nt + l15;
      size_t base = ((size_t)b * 2048 + n) * 512;
#pragma unroll
      for (int ot = 0; ot < 4; ++ot) {
        int o = o0 + wo + 16 * ot + 4 * quad;
        short4v pk;
#pragma unroll
        for (int r = 0; r < 4; ++r) pk[r] = bf16r(kscale * acc[ot][nt][r]);
        *(short4v*)&Yt[base + o] = pk;
      }
    }
  } else {
    // V: column permute within 32-groups: col' = 32-grp + q*8 + t*4 + jj
#pragma unroll
    for (int ot = 0; ot < 4; ++ot)
#pragma unroll
      for (int r = 0; r < 4; ++r) {
        int ch = o0 - 512 + wo + 16 * ot + 4 * quad + r;
#pragma unroll
        for (int nt = 0; nt < 4; ++nt) {
          int colp = n0 + wn + 32 * (nt >> 1) + (l15 >> 2) * 8 +
                     (nt & 1) * 4 + (l15 & 3);
          Yv[((size_t)b * 512 + ch) * 2048 + colp] =
              (_Float16)acc[ot][nt][r];
        }
      }
  }
}

// ---------------------------------------------------------------------------
// Kernel 3: k2m[(b*8+h)*M+m] = mask ? 0.25*sum_d kbT[m][h*64+d]^2 : +INF
// (kbT holds -2K, hence the 0.25 correction.)
// ---------------------------------------------------------------------------
__global__ __launch_bounds__(256) void k2_kernel(const short* __restrict__ kbT,
                                                 const int* __restrict__ mask,
                                                 float* __restrict__ k2m) {
  int w = threadIdx.x >> 6, l = threadIdx.x & 63;
  int row = blockIdx.x * 4 + w;  // row in [0, B*M)
  int b = row >> 11, m = row & 2047;
  short8 v = *(const short8*)&kbT[(size_t)row * 512 + 8 * l];
  float s = 0.f;
#pragma unroll
  for (int e = 0; e < 8; ++e) {
    float f = bf2f(v[e]);
    s += f * f;
  }
  s += __shfl_xor(s, 1);
  s += __shfl_xor(s, 2);
  s += __shfl_xor(s, 4);
  int mv = mask[row];
  if ((l & 7) == 0) {
    int h = l >> 3;
    k2m[((size_t)b * 8 + h) * 2048 + m] = mv ? 0.25f * s : __builtin_inff();
  }
}

// ---------------------------------------------------------------------------
// Kernel 4: L2-distance flash attention, S^T formulation, zero LDS and zero
// cross-lane ops in the j-loop.
//   S^T = (-2K)*Q^T with accumulator pre-loaded with q2+k2 (so the MFMA
//   output IS d2).  k2 per row r=4*quad+r via per-quad float4 broadcast load.
//   P lands in 16x16x16f16 B-fragment layout (k=4*quad+r, n=l15): PV runs
//   directly from registers.  V^T A-fragments are half8 16B loads (column
//   permute done at V-write time) — each feeds two PV MFMAs.
// Block 256 = 4 waves: jh=w&1 j-half, iw=w>>1 i-subtile; 32 q-rows/block.
// Grid 2048, XCD-swizzled.  Combine halves = plain add (max==0 softmax).
// ---------------------------------------------------------------------------
__global__ __launch_bounds__(256, 4) void attn_kernel(
    const short* __restrict__ qb, const short* __restrict__ kbT,
    const _Float16* __restrict__ vb, const float* __restrict__ k2m,
    short* __restrict__ attn_t) {
  const int bid = blockIdx.x;
  const int rr = bid & 7, qq = bid >> 3;       // rr ~ XCD
  const int iblk = qq >> 2;                    // [0,64)
  const int g = rr * 4 + (qq & 3);             // bh in [0,32)
  const int h = g & 7, b = g >> 3;
  const int i0 = iblk * 32;

  const int tid = threadIdx.x;
  const int w = tid >> 6, l = tid & 63, quad = l >> 4, l15 = l & 15;
  const int jh = w & 1, iw = w >> 1;

  __shared__ float o_lds[64][34];  // [d][i_local], pad 34 (2-way = free)
  __shared__ float l_lds[32];

  const short* qrow = qb + ((size_t)b * N_ + i0 + 16 * iw + l15) * 512 + h * 64;
  const short* kbase = kbT + (size_t)b * M_ * 512 + h * 64;
  const _Float16* vbase = vb + ((size_t)b * 512 + h * 64) * (size_t)M_;
  const float* k2b = k2m + ((size_t)b * 8 + h) * M_;

  // Q^T B-fragments (n=i=l15, k=d=8*quad+jj) + q2 (per-lane scalar)
  short8 qa0 = *(const short8*)&qrow[8 * quad];
  short8 qa1 = *(const short8*)&qrow[32 + 8 * quad];
  float q2p = 0.f;
#pragma unroll
  for (int jj = 0; jj < 8; ++jj) {
    float f0 = bf2f(qa0[jj]), f1 = bf2f(qa1[jj]);
    q2p += f0 * f0 + f1 * f1;
  }
  q2p += __shfl_xor(q2p, 16);
  q2p += __shfl_xor(q2p, 32);
  const float q2c = q2p;  // q2 for column i=l15, all lanes

  floatx4 accO[4];  // O^T C-layout: (d = 16*dt+4*quad+r, i = l15)
#pragma unroll
  for (int dt = 0; dt < 4; ++dt)
#pragma unroll
    for (int r = 0; r < 4; ++r) accO[dt][r] = 0.f;
  float lsum = 0.f;  // partial l for column i=l15 (this lane's j's)

  const int jbeg = jh * 1024;
  const float C2 = -0.18033688011112042f;  // -0.125 * log2(e)

  for (int j0 = jbeg; j0 < jbeg + 1024; j0 += 64) {
    half4 pb[4];  // P B-fragments per 16-j tile
#pragma unroll
    for (int jt = 0; jt < 4; ++jt) {
      // k2 for rows j = j0+16*jt+4*quad+r: per-quad broadcast float4 load
      float4 k2v = *(const float4*)&k2b[j0 + 16 * jt + 4 * quad];
      const short* krow = kbase + (size_t)(j0 + 16 * jt + l15) * 512;
      short8 k0 = *(const short8*)&krow[8 * quad];
      short8 k1 = *(const short8*)&krow[32 + 8 * quad];
      floatx4 a;
      a[0] = q2c + k2v.x;
      a[1] = q2c + k2v.y;
      a[2] = q2c + k2v.z;
      a[3] = q2c + k2v.w;
      // S^T: A = -2K (m=j), B = Q^T (n=i); result = q2+k2-2qk = d2
      a = __builtin_amdgcn_mfma_f32_16x16x32_bf16(k0, qa0, a, 0, 0, 0);
      a = __builtin_amdgcn_mfma_f32_16x16x32_bf16(k1, qa1, a, 0, 0, 0);
#pragma unroll
      for (int r = 0; r < 4; ++r) {
        float d2 = fmaxf(a[r], 1e-12f);
        float p = __builtin_amdgcn_exp2f(C2 * __builtin_amdgcn_sqrtf(d2));
        lsum += p;
        pb[jt][r] = (_Float16)p;
      }
    }

    // ---- O^T += V^T P^T, all-register operands, 16B V loads ----
#pragma unroll
    for (int dt = 0; dt < 4; ++dt) {
      const _Float16* vrow = vbase + (size_t)(16 * dt + l15) * M_ + j0;
      half8 h0 = *(const half8*)&vrow[8 * quad];        // tiles jt=0,1
      half8 h1 = *(const half8*)&vrow[32 + 8 * quad];   // tiles jt=2,3
      half4 va;
      va[0] = h0[0]; va[1] = h0[1]; va[2] = h0[2]; va[3] = h0[3];
      accO[dt] = __builtin_amdgcn_mfma_f32_16x16x16f16(va, pb[0], accO[dt], 0, 0, 0);
      va[0] = h0[4]; va[1] = h0[5]; va[2] = h0[6]; va[3] = h0[7];
      accO[dt] = __builtin_amdgcn_mfma_f32_16x16x16f16(va, pb[1], accO[dt], 0, 0, 0);
      va[0] = h1[0]; va[1] = h1[1]; va[2] = h1[2]; va[3] = h1[3];
      accO[dt] = __builtin_amdgcn_mfma_f32_16x16x16f16(va, pb[2], accO[dt], 0, 0, 0);
      va[0] = h1[4]; va[1] = h1[5]; va[2] = h1[6]; va[3] = h1[7];
      accO[dt] = __builtin_amdgcn_mfma_f32_16x16x16f16(va, pb[3], accO[dt], 0, 0, 0);
    }
  }

  // total l for column i=l15
  lsum += __shfl_xor(lsum, 16);
  lsum += __shfl_xor(lsum, 32);

  // ---- combine the two j-halves (plain add; max==0 softmax) ----
  if (jh == 1) {
#pragma unroll
    for (int dt = 0; dt < 4; ++dt)
#pragma unroll
      for (int r = 0; r < 4; ++r)
        o_lds[16 * dt + 4 * quad + r][16 * iw + l15] = accO[dt][r];
    if (quad == 0) l_lds[16 * iw + l15] = lsum;
  }
  __syncthreads();
  if (jh == 0) {
    float rl = 1.0f / (lsum + l_lds[16 * iw + l15]);
    size_t base = ((size_t)b * N_ + i0 + 16 * iw + l15) * 512 + h * 64;
#pragma unroll
    for (int dt = 0; dt < 4; ++dt)
#pragma unroll
      for (int r = 0; r < 4; ++r) {
        int d = 16 * dt + 4 * quad + r;
        float o = accO[dt][r] + o_lds[d][16 * iw + l15];
        attn_t[base + d] = bf16r(o * rl);
      }
  }
}

// ---------------------------------------------------------------------------
extern "C" void kernel_launch(void* const* d_in, const int* in_sizes, int n_in,
                              void* d_out, int out_size, void* d_ws,
                              size_t ws_size, hipStream_t stream) {
  const float* fmap = (const float*)d_in[0];
  const float* context = (const float*)d_in[1];
  const int* mask = (const int*)d_in[2];
  const float* gamma = (const float*)d_in[3];
  const float* gamma_ctx = (const float*)d_in[4];
  const float* Wq = (const float*)d_in[5];
  const float* Wkv = (const float*)d_in[6];
  const float* Wout = (const float*)d_in[7];
  float* out = (float*)d_out;

  char* ws = (char*)d_ws;
  short* fmap_t = (short*)ws;                 // 4 MB
  short* ctx_t = fmap_t + 2097152;            // 4 MB
  short* qb = ctx_t + 2097152;                // 8 MB
  short* kbT = qb + 4194304;                  // 8 MB (-2K)
  _Float16* vb = (_Float16*)(kbT + 4194304);  // 8 MB (f16, col-permuted)
  short* attn_t = (short*)(vb + 4194304);     // 8 MB
  float* k2m = (float*)(attn_t + 4194304);    // 256 KB
  short* whi = (short*)(k2m + 65536);         // 1 MB
  short* wlo = whi + 524288;                  // 1 MB

  dim3 blk64x4(64, 4);
  wsplit_kernel<<<dim3(256, 3), 256, 0, stream>>>(Wq, Wkv, Wout, gamma,
                                                  gamma_ctx, whi, wlo);
  colnorm_t_kernel<<<dim3(N_ / 64, B_), blk64x4, 0, stream>>>(fmap, fmap_t, N_);
  colnorm_t_kernel<<<dim3(M_ / 64, B_), blk64x4, 0, stream>>>(context, ctx_t,
                                                              M_);
  gemm_mfma_kernel<1><<<dim3(16, 4, B_), 256, 0, stream>>>(
      whi, wlo, fmap_t, nullptr, qb, nullptr, DIM_, DINNER_);
  gemm_mfma_kernel<2><<<dim3(16, 8, B_), 256, 0, stream>>>(
      whi + 131072, wlo + 131072, ctx_t, nullptr, kbT, vb, DIM_, 2 * DINNER_);
  k2_kernel<<<dim3(B_ * M_ / 4), 256, 0, stream>>>(kbT, mask, k2m);
  attn_kernel<<<dim3(2048), 256, 0, stream>>>(qb, kbT, vb, k2m, attn_t);
  gemm_mfma_kernel<0><<<dim3(16, 2, B_), 256, 0, stream>>>(
      whi + 393216, wlo + 393216, attn_t, out, nullptr, nullptr, DINNER_,
      DIM_);
}

// Round 10
// 246.793 us; speedup vs baseline: 2.0973x; 1.7099x over previous
//
#include <hip/hip_runtime.h>
#include <hip/hip_bf16.h>

// Problem constants
#define B_ 4
#define DIM_ 256
#define N_ 2048
#define M_ 2048
#define HEADS_ 8
#define DHEAD_ 64
#define DINNER_ 512

typedef __attribute__((ext_vector_type(8))) short short8;
typedef __attribute__((ext_vector_type(4))) short short4v;
typedef __attribute__((ext_vector_type(4))) float floatx4;
typedef __attribute__((ext_vector_type(4))) _Float16 half4;
typedef __attribute__((ext_vector_type(8))) _Float16 half8;

#if defined(__has_builtin)
#if __has_builtin(__builtin_amdgcn_global_load_lds)
#define HAS_DMA 1
#endif
#endif

typedef __attribute__((address_space(1))) const void gvoid_t;
typedef __attribute__((address_space(3))) void lvoid_t;

__device__ inline short bf16r(float x) {  // RNE f32->bf16 (bit form)
  unsigned u = __float_as_uint(x);
  unsigned r = (u + 0x7fffu + ((u >> 16) & 1u)) >> 16;
  return (short)r;
}
__device__ inline float bf2f(short b) {
  return __uint_as_float(((unsigned)(unsigned short)b) << 16);
}

// ---------------------------------------------------------------------------
// Kernel 0: one-shot W split: whi/wlo bf16 planes of (W * gamma).
// ---------------------------------------------------------------------------
__global__ __launch_bounds__(256) void wsplit_kernel(
    const float* __restrict__ Wq, const float* __restrict__ Wkv,
    const float* __restrict__ Wout, const float* __restrict__ gamma,
    const float* __restrict__ gctx, short* __restrict__ whi,
    short* __restrict__ wlo) {
  const int y = blockIdx.y;
  const int gsz[3] = {32768, 65536, 32768};  // float4 groups per matrix
  const int goff[3] = {0, 131072, 393216};   // element offset in planes
  int gidx = blockIdx.x * 256 + threadIdx.x;
  if (gidx >= gsz[y]) return;
  const float* W = (y == 0) ? Wq : (y == 1) ? Wkv : Wout;
  const int cmask = (y == 2) ? 511 : 255;
  int e0 = gidx * 4;
  int c = e0 & cmask;
  float4 wv = *(const float4*)&W[e0];
  if (y < 2) {
    const float* g = (y == 0) ? gamma : gctx;
    float4 g4 = *(const float4*)&g[c];
    wv.x *= g4.x; wv.y *= g4.y; wv.z *= g4.z; wv.w *= g4.w;
  }
  float vv[4] = {wv.x, wv.y, wv.z, wv.w};
  short4v hi, lo;
#pragma unroll
  for (int e = 0; e < 4; ++e) {
    short hb = bf16r(vv[e]);
    hi[e] = hb;
    lo[e] = bf16r(vv[e] - bf2f(hb));
  }
  *(short4v*)&whi[goff[y] + e0] = hi;
  *(short4v*)&wlo[goff[y] + e0] = lo;
}

// ---------------------------------------------------------------------------
// Kernel 1: channel RMSNorm -> bf16 transposed, coalesced via LDS transpose.
// ---------------------------------------------------------------------------
__global__ __launch_bounds__(256) void colnorm_t_kernel(
    const float* __restrict__ x, short* __restrict__ xt, int NN) {
  int b = blockIdx.y;
  int tx = threadIdx.x, ty = threadIdx.y;
  int n0 = blockIdx.x * 64, n = n0 + tx;
  const float* xb = x + (size_t)b * 256 * NN;

  float ssq = 0.f;
  for (int c = ty; c < 256; c += 4) {
    float v = xb[(size_t)c * NN + n];
    ssq += v * v;
  }
  __shared__ float red[4][64];
  __shared__ float scl[64];
  __shared__ float t[64][65];
  red[ty][tx] = ssq;
  __syncthreads();
  if (ty == 0) {
    float s = red[0][tx] + red[1][tx] + red[2][tx] + red[3][tx];
    scl[tx] = 16.0f / fmaxf(sqrtf(s), 1e-12f);
  }
  int tid = ty * 64 + tx;
  int row = tid >> 2, cg = tid & 3;
  for (int c0 = 0; c0 < 256; c0 += 64) {
    __syncthreads();
    for (int cc = ty; cc < 64; cc += 4) t[cc][tx] = xb[(size_t)(c0 + cc) * NN + n];
    __syncthreads();
    float sc = scl[row];
    short8 o0v, o1v;
#pragma unroll
    for (int e = 0; e < 8; ++e) {
      o0v[e] = bf16r(t[cg * 16 + e][row] * sc);
      o1v[e] = bf16r(t[cg * 16 + 8 + e][row] * sc);
    }
    size_t base = ((size_t)b * NN + n0 + row) * 256 + c0 + cg * 16;
    *(short8*)&xt[base] = o0v;
    *(short8*)&xt[base + 8] = o1v;
  }
}

// ---------------------------------------------------------------------------
// Kernel 2: MFMA GEMM from pre-split bf16 W planes.
// EPI 0: fp32 out-proj [b][o][2048].
// EPI 1: bf16 [b][n][512] (q).
// EPI 2: K (o0<512): -2K in per-(b,h) 64-chunk tiles [bh][chunk][jrow][d'],
//        d-group swizzled (g^=jrow&7), 8KB/tile, + fused k2m (mask -> +inf).
//        V (o0>=512): f16 tiles [bh][chunk][drow][col'], col' = PV-A-frag
//        permute of j, group-swizzled (g^=drow&7).
// ---------------------------------------------------------------------------
template <int EPI>
__global__ __launch_bounds__(256) void gemm_mfma_kernel(
    const short* __restrict__ whi, const short* __restrict__ wlo,
    const short* __restrict__ Xt, float* __restrict__ Yf,
    short* __restrict__ Yt, _Float16* __restrict__ Yv,
    const int* __restrict__ maskp, float* __restrict__ k2m, int C, int O) {
  const int b = blockIdx.z;
  const int n0 = blockIdx.x * 128;
  const int o0 = blockIdx.y * 128;
  const int tid = threadIdx.x;
  const int w = tid >> 6, l = tid & 63, quad = l >> 4, l15 = l & 15;
  const int wo = (w >> 1) * 64, wn = (w & 1) * 64;

  __shared__ __align__(16) short Wa[2][128][40];
  __shared__ __align__(16) short Xb[128][40];

  floatx4 acc[4][4];
#pragma unroll
  for (int ot = 0; ot < 4; ++ot)
#pragma unroll
    for (int nt = 0; nt < 4; ++nt)
#pragma unroll
      for (int r = 0; r < 4; ++r) acc[ot][nt][r] = 0.f;

  for (int c0 = 0; c0 < C; c0 += 32) {
    __syncthreads();
#pragma unroll
    for (int it = 0; it < 2; ++it) {
      int lin = tid + it * 256;
      int row = lin >> 2, sg = (lin & 3) * 8;
      size_t src = (size_t)(o0 + row) * C + c0 + sg;
      *(short8*)&Wa[0][row][sg] = *(const short8*)&whi[src];
      *(short8*)&Wa[1][row][sg] = *(const short8*)&wlo[src];
    }
#pragma unroll
    for (int it = 0; it < 2; ++it) {
      int lin = tid + it * 256;
      int nn = lin >> 2, sg = (lin & 3) * 8;
      *(short8*)&Xb[nn][sg] =
          *(const short8*)&Xt[((size_t)b * 2048 + n0 + nn) * C + c0 + sg];
    }
    __syncthreads();

    short8 ah[4], al[4], bx[4];
#pragma unroll
    for (int ot = 0; ot < 4; ++ot) {
      ah[ot] = *(const short8*)&Wa[0][wo + 16 * ot + l15][8 * quad];
      al[ot] = *(const short8*)&Wa[1][wo + 16 * ot + l15][8 * quad];
    }
#pragma unroll
    for (int nt = 0; nt < 4; ++nt)
      bx[nt] = *(const short8*)&Xb[wn + 16 * nt + l15][8 * quad];
#pragma unroll
    for (int ot = 0; ot < 4; ++ot)
#pragma unroll
      for (int nt = 0; nt < 4; ++nt) {
        acc[ot][nt] =
            __builtin_amdgcn_mfma_f32_16x16x32_bf16(al[ot], bx[nt], acc[ot][nt], 0, 0, 0);
        acc[ot][nt] =
            __builtin_amdgcn_mfma_f32_16x16x32_bf16(ah[ot], bx[nt], acc[ot][nt], 0, 0, 0);
      }
  }

  if (EPI == 0) {
#pragma unroll
    for (int ot = 0; ot < 4; ++ot)
#pragma unroll
      for (int r = 0; r < 4; ++r) {
        int o = o0 + wo + 16 * ot + 4 * quad + r;
#pragma unroll
        for (int nt = 0; nt < 4; ++nt)
          Yf[((size_t)b * O + o) * 2048 + n0 + wn + 16 * nt + l15] =
              acc[ot][nt][r];
      }
  } else if (EPI == 1) {
#pragma unroll
    for (int nt = 0; nt < 4; ++nt) {
      int n = n0 + wn + 16 * nt + l15;
      size_t base = ((size_t)b * 2048 + n) * 512;
#pragma unroll
      for (int ot = 0; ot < 4; ++ot) {
        int o = o0 + wo + 16 * ot + 4 * quad;
        short4v pk;
#pragma unroll
        for (int r = 0; r < 4; ++r) pk[r] = bf16r(acc[ot][nt][r]);
        *(short4v*)&Yt[base + o] = pk;
      }
    }
  } else if (EPI == 2 && o0 < 512) {
    // K part: one head per wave (64 channels), -2 scale, swizzled tiles + k2.
    const int head = (o0 + wo) >> 6;
    const int bh = b * 8 + head;
    float k2p[4] = {0.f, 0.f, 0.f, 0.f};
#pragma unroll
    for (int nt = 0; nt < 4; ++nt) {
      int m = n0 + wn + 16 * nt + l15;
      int chunk = m >> 6, mrow = m & 63;
      size_t tbase = (((size_t)bh * 32 + chunk) * 64 + mrow) * 64;
      int sw = mrow & 7;
#pragma unroll
      for (int ot = 0; ot < 4; ++ot) {
        int d0 = 16 * ot + 4 * quad;
        short4v pk;
#pragma unroll
        for (int r = 0; r < 4; ++r) {
          short pv = bf16r(-2.0f * acc[ot][nt][r]);
          pk[r] = pv;
          float kr = bf2f(pv);
          k2p[nt] += kr * kr;
        }
        *(short4v*)&Yt[tbase + (size_t)(((d0 >> 3) ^ sw) << 3) + (d0 & 7)] = pk;
      }
    }
#pragma unroll
    for (int nt = 0; nt < 4; ++nt) {
      float s = k2p[nt];
      s += __shfl_xor(s, 16);
      s += __shfl_xor(s, 32);
      if (quad == 0) {
        int m = n0 + wn + 16 * nt + l15;
        int mv = maskp[b * 2048 + m];
        k2m[(size_t)bh * 2048 + m] = mv ? 0.25f * s : __builtin_inff();
      }
    }
  } else {
    // V part: f16, column permute (PV A-frag order) + group swizzle.
    const int chv = o0 - 512 + wo;  // base channel for this wave (one head)
    const int bh = b * 8 + (chv >> 6);
#pragma unroll
    for (int nt = 0; nt < 4; ++nt) {
      int j = n0 + wn + 16 * nt + l15;
      int chunk = j >> 6, jr = j & 63;
      int jrem = jr & 31;
      int colp = 32 * (jr >> 5) + ((jrem >> 2) & 3) * 8 + (jrem >> 4) * 4 +
                 (jrem & 3);
      size_t cbase = ((size_t)bh * 32 + chunk) * 4096;
#pragma unroll
      for (int ot = 0; ot < 4; ++ot)
#pragma unroll
        for (int r = 0; r < 4; ++r) {
          int drow = (chv + 16 * ot + 4 * quad + r) & 63;
          Yv[cbase + drow * 64 + (((colp >> 3) ^ (drow & 7)) << 3) +
             (colp & 7)] = (_Float16)acc[ot][nt][r];
        }
    }
  }
}

// ---------------------------------------------------------------------------
// Kernel 3: L2-distance flash attention, DMA-staged double-buffered j-loop.
// Block 256 = 4 waves x 16 i-rows (64 rows); all waves share the j-walk.
// Per 64-j chunk: K tile (8KB, -2K bf16 swizzled) and V tile (8KB f16
// permuted+swizzled) DMA'd global->LDS; one barrier per chunk; DMA of chunk
// c+1 overlaps compute of chunk c (m97 pattern).  S^T formulation: MFMA acc
// pre-init q2, k2 added post-MFMA; P feeds 16x16x16f16 PV from registers.
// Grid 1024 = 32 bh x 32 iblk (XCD-swizzled) = exactly 4 blocks/CU.
// ---------------------------------------------------------------------------
__global__ __launch_bounds__(256, 4) void attn_kernel(
    const short* __restrict__ qb, const short* __restrict__ kc,
    const _Float16* __restrict__ vc, const float* __restrict__ k2m,
    short* __restrict__ attn_t) {
  const int bid = blockIdx.x;
  const int rr = bid & 7, qq = bid >> 3;  // rr ~ XCD
  const int bh = rr * 4 + (qq >> 5);      // 4 bh per XCD
  const int iblk = qq & 31;
  const int h = bh & 7, b = bh >> 3;
  const int i0 = iblk * 64;

  const int tid = threadIdx.x;
  const int w = tid >> 6, l = tid & 63, quad = l >> 4, l15 = l & 15;

  __shared__ __align__(16) short kbuf[2][4096];
  __shared__ __align__(16) short vbuf[2][4096];

  const short* qrow =
      qb + ((size_t)b * 2048 + i0 + 16 * w + l15) * 512 + h * 64;
  const short* kcb = kc + (size_t)bh * 32 * 4096;
  const _Float16* vcb = vc + (size_t)bh * 32 * 4096;
  const float* k2b = k2m + (size_t)bh * 2048;

  // Q^T B-fragments (n=i=l15, k=d=8*quad+jj) + q2 (per-lane scalar)
  short8 qa0 = *(const short8*)&qrow[8 * quad];
  short8 qa1 = *(const short8*)&qrow[32 + 8 * quad];
  float q2p = 0.f;
#pragma unroll
  for (int jj = 0; jj < 8; ++jj) {
    float f0 = bf2f(qa0[jj]), f1 = bf2f(qa1[jj]);
    q2p += f0 * f0 + f1 * f1;
  }
  q2p += __shfl_xor(q2p, 16);
  q2p += __shfl_xor(q2p, 32);
  const float q2c = q2p;

  floatx4 accO[4];
#pragma unroll
  for (int dt = 0; dt < 4; ++dt)
#pragma unroll
    for (int r = 0; r < 4; ++r) accO[dt][r] = 0.f;
  float lsum = 0.f;

  const float C2 = -0.18033688011112042f;  // -0.125 * log2(e)
  const int sx = l15 & 7;                  // swizzle key

  // stage chunk c into buffer p: 4 DMA issues per wave (2 K segs, 2 V segs)
  auto stage = [&](int c, int p) {
    const short* ks = kcb + (size_t)c * 4096 + (2 * w) * 512 + l * 8;
    const _Float16* vs = vcb + (size_t)c * 4096 + (2 * w) * 512 + l * 8;
#ifdef HAS_DMA
    __builtin_amdgcn_global_load_lds((gvoid_t*)ks,
                                     (lvoid_t*)&kbuf[p][(2 * w) * 512], 16, 0, 0);
    __builtin_amdgcn_global_load_lds((gvoid_t*)(ks + 512),
                                     (lvoid_t*)&kbuf[p][(2 * w + 1) * 512], 16, 0, 0);
    __builtin_amdgcn_global_load_lds((gvoid_t*)vs,
                                     (lvoid_t*)&vbuf[p][(2 * w) * 512], 16, 0, 0);
    __builtin_amdgcn_global_load_lds((gvoid_t*)(vs + 512),
                                     (lvoid_t*)&vbuf[p][(2 * w + 1) * 512], 16, 0, 0);
#else
    *(short8*)&kbuf[p][(2 * w) * 512 + l * 8] = *(const short8*)ks;
    *(short8*)&kbuf[p][(2 * w + 1) * 512 + l * 8] = *(const short8*)(ks + 512);
    *(half8*)&vbuf[p][(2 * w) * 512 + l * 8] = *(const half8*)vs;
    *(half8*)&vbuf[p][(2 * w + 1) * 512 + l * 8] = *(const half8*)(vs + 512);
#endif
  };

  stage(0, 0);
  for (int c = 0; c < 32; ++c) {
    __syncthreads();  // drains chunk-c DMA (vmcnt(0) before barrier)
    if (c < 31) stage(c + 1, (c + 1) & 1);
    const int p = c & 1;
    const int j0 = c * 64;

    half4 pb[4];
#pragma unroll
    for (int jt = 0; jt < 4; ++jt) {
      float4 k2v = *(const float4*)&k2b[j0 + 16 * jt + 4 * quad];
      const short* kr = &kbuf[p][(16 * jt + l15) * 64];
      short8 k0 = *(const short8*)&kr[(quad ^ sx) << 3];
      short8 k1 = *(const short8*)&kr[((quad + 4) ^ sx) << 3];
      floatx4 a;
      a[0] = q2c; a[1] = q2c; a[2] = q2c; a[3] = q2c;
      a = __builtin_amdgcn_mfma_f32_16x16x32_bf16(k0, qa0, a, 0, 0, 0);
      a = __builtin_amdgcn_mfma_f32_16x16x32_bf16(k1, qa1, a, 0, 0, 0);
      float k2a[4] = {k2v.x, k2v.y, k2v.z, k2v.w};
#pragma unroll
      for (int r = 0; r < 4; ++r) {
        float d2 = fmaxf(a[r] + k2a[r], 1e-12f);
        float pv = __builtin_amdgcn_exp2f(C2 * __builtin_amdgcn_sqrtf(d2));
        lsum += pv;
        pb[jt][r] = (_Float16)pv;
      }
    }

#pragma unroll
    for (int dt = 0; dt < 4; ++dt) {
      const _Float16* vr = (const _Float16*)&vbuf[p][(16 * dt + l15) * 64];
      half8 h0 = *(const half8*)&vr[(quad ^ sx) << 3];
      half8 h1 = *(const half8*)&vr[((quad + 4) ^ sx) << 3];
      half4 va;
      va[0] = h0[0]; va[1] = h0[1]; va[2] = h0[2]; va[3] = h0[3];
      accO[dt] = __builtin_amdgcn_mfma_f32_16x16x16f16(va, pb[0], accO[dt], 0, 0, 0);
      va[0] = h0[4]; va[1] = h0[5]; va[2] = h0[6]; va[3] = h0[7];
      accO[dt] = __builtin_amdgcn_mfma_f32_16x16x16f16(va, pb[1], accO[dt], 0, 0, 0);
      va[0] = h1[0]; va[1] = h1[1]; va[2] = h1[2]; va[3] = h1[3];
      accO[dt] = __builtin_amdgcn_mfma_f32_16x16x16f16(va, pb[2], accO[dt], 0, 0, 0);
      va[0] = h1[4]; va[1] = h1[5]; va[2] = h1[6]; va[3] = h1[7];
      accO[dt] = __builtin_amdgcn_mfma_f32_16x16x16f16(va, pb[3], accO[dt], 0, 0, 0);
    }
  }

  // total l for column i=l15 (reduce over quads), then direct store
  lsum += __shfl_xor(lsum, 16);
  lsum += __shfl_xor(lsum, 32);
  float rl = 1.0f / lsum;
  size_t base = ((size_t)b * 2048 + i0 + 16 * w + l15) * 512 + h * 64;
#pragma unroll
  for (int dt = 0; dt < 4; ++dt)
#pragma unroll
    for (int r = 0; r < 4; ++r)
      attn_t[base + 16 * dt + 4 * quad + r] = bf16r(accO[dt][r] * rl);
}

// ---------------------------------------------------------------------------
extern "C" void kernel_launch(void* const* d_in, const int* in_sizes, int n_in,
                              void* d_out, int out_size, void* d_ws,
                              size_t ws_size, hipStream_t stream) {
  const float* fmap = (const float*)d_in[0];
  const float* context = (const float*)d_in[1];
  const int* mask = (const int*)d_in[2];
  const float* gamma = (const float*)d_in[3];
  const float* gamma_ctx = (const float*)d_in[4];
  const float* Wq = (const float*)d_in[5];
  const float* Wkv = (const float*)d_in[6];
  const float* Wout = (const float*)d_in[7];
  float* out = (float*)d_out;

  char* ws = (char*)d_ws;
  short* fmap_t = (short*)ws;                 // 4 MB
  short* ctx_t = fmap_t + 2097152;            // 4 MB
  short* qb = ctx_t + 2097152;                // 8 MB
  short* kc = qb + 4194304;                   // 8 MB (-2K, swizzled tiles)
  _Float16* vc = (_Float16*)(kc + 4194304);   // 8 MB (f16, permuted tiles)
  short* attn_t = (short*)(vc + 4194304);     // 8 MB
  float* k2m = (float*)(attn_t + 4194304);    // 256 KB
  short* whi = (short*)(k2m + 65536);         // 1 MB
  short* wlo = whi + 524288;                  // 1 MB

  dim3 blk64x4(64, 4);
  wsplit_kernel<<<dim3(256, 3), 256, 0, stream>>>(Wq, Wkv, Wout, gamma,
                                                  gamma_ctx, whi, wlo);
  colnorm_t_kernel<<<dim3(N_ / 64, B_), blk64x4, 0, stream>>>(fmap, fmap_t, N_);
  colnorm_t_kernel<<<dim3(M_ / 64, B_), blk64x4, 0, stream>>>(context, ctx_t,
                                                              M_);
  gemm_mfma_kernel<1><<<dim3(16, 4, B_), 256, 0, stream>>>(
      whi, wlo, fmap_t, nullptr, qb, nullptr, nullptr, nullptr, DIM_, DINNER_);
  gemm_mfma_kernel<2><<<dim3(16, 8, B_), 256, 0, stream>>>(
      whi + 131072, wlo + 131072, ctx_t, nullptr, kc, vc, mask, k2m, DIM_,
      2 * DINNER_);
  attn_kernel<<<dim3(1024), 256, 0, stream>>>(qb, kc, vc, k2m, attn_t);
  gemm_mfma_kernel<0><<<dim3(16, 2, B_), 256, 0, stream>>>(
      whi + 393216, wlo + 393216, attn_t, out, nullptr, nullptr, nullptr,
      nullptr, DINNER_, DIM_);
}

// Round 11
// 215.770 us; speedup vs baseline: 2.3988x; 1.1438x over previous
//
#include <hip/hip_runtime.h>
#include <hip/hip_bf16.h>

// Problem constants
#define B_ 4
#define DIM_ 256
#define N_ 2048
#define M_ 2048
#define HEADS_ 8
#define DHEAD_ 64
#define DINNER_ 512

typedef __attribute__((ext_vector_type(8))) short short8;
typedef __attribute__((ext_vector_type(4))) short short4v;
typedef __attribute__((ext_vector_type(4))) float floatx4;
typedef __attribute__((ext_vector_type(4))) _Float16 half4;
typedef __attribute__((ext_vector_type(8))) _Float16 half8;

#if defined(__has_builtin)
#if __has_builtin(__builtin_amdgcn_global_load_lds)
#define HAS_DMA 1
#endif
#endif

typedef __attribute__((address_space(1))) const void gvoid_t;
typedef __attribute__((address_space(3))) void lvoid_t;

__device__ inline short bf16r(float x) {  // RNE f32->bf16 (bit form)
  unsigned u = __float_as_uint(x);
  unsigned r = (u + 0x7fffu + ((u >> 16) & 1u)) >> 16;
  return (short)r;
}
__device__ inline float bf2f(short b) {
  return __uint_as_float(((unsigned)(unsigned short)b) << 16);
}

// ---------------------------------------------------------------------------
// Kernel 0: one-shot W split: whi/wlo bf16 planes of (W * gamma).
// ---------------------------------------------------------------------------
__global__ __launch_bounds__(256) void wsplit_kernel(
    const float* __restrict__ Wq, const float* __restrict__ Wkv,
    const float* __restrict__ Wout, const float* __restrict__ gamma,
    const float* __restrict__ gctx, short* __restrict__ whi,
    short* __restrict__ wlo) {
  const int y = blockIdx.y;
  const int gsz[3] = {32768, 65536, 32768};  // float4 groups per matrix
  const int goff[3] = {0, 131072, 393216};   // element offset in planes
  int gidx = blockIdx.x * 256 + threadIdx.x;
  if (gidx >= gsz[y]) return;
  const float* W = (y == 0) ? Wq : (y == 1) ? Wkv : Wout;
  const int cmask = (y == 2) ? 511 : 255;
  int e0 = gidx * 4;
  int c = e0 & cmask;
  float4 wv = *(const float4*)&W[e0];
  if (y < 2) {
    const float* g = (y == 0) ? gamma : gctx;
    float4 g4 = *(const float4*)&g[c];
    wv.x *= g4.x; wv.y *= g4.y; wv.z *= g4.z; wv.w *= g4.w;
  }
  float vv[4] = {wv.x, wv.y, wv.z, wv.w};
  short4v hi, lo;
#pragma unroll
  for (int e = 0; e < 4; ++e) {
    short hb = bf16r(vv[e]);
    hi[e] = hb;
    lo[e] = bf16r(vv[e] - bf2f(hb));
  }
  *(short4v*)&whi[goff[y] + e0] = hi;
  *(short4v*)&wlo[goff[y] + e0] = lo;
}

// ---------------------------------------------------------------------------
// Kernel 1: fused channel RMSNorm -> bf16 transposed for BOTH tensors.
// grid (NN/64, B, 2): z=0 fmap->fmap_t, z=1 context->ctx_t.  block (64,4).
// ---------------------------------------------------------------------------
__global__ __launch_bounds__(256) void colnorm_t_kernel(
    const float* __restrict__ xf, const float* __restrict__ xc,
    short* __restrict__ xtf, short* __restrict__ xtc, int NN) {
  const float* x = (blockIdx.z == 0) ? xf : xc;
  short* xt = (blockIdx.z == 0) ? xtf : xtc;
  int b = blockIdx.y;
  int tx = threadIdx.x, ty = threadIdx.y;
  int n0 = blockIdx.x * 64, n = n0 + tx;
  const float* xb = x + (size_t)b * 256 * NN;

  float ssq = 0.f;
  for (int c = ty; c < 256; c += 4) {
    float v = xb[(size_t)c * NN + n];
    ssq += v * v;
  }
  __shared__ float red[4][64];
  __shared__ float scl[64];
  __shared__ float t[64][65];
  red[ty][tx] = ssq;
  __syncthreads();
  if (ty == 0) {
    float s = red[0][tx] + red[1][tx] + red[2][tx] + red[3][tx];
    scl[tx] = 16.0f / fmaxf(sqrtf(s), 1e-12f);
  }
  int tid = ty * 64 + tx;
  int row = tid >> 2, cg = tid & 3;
  for (int c0 = 0; c0 < 256; c0 += 64) {
    __syncthreads();
    for (int cc = ty; cc < 64; cc += 4) t[cc][tx] = xb[(size_t)(c0 + cc) * NN + n];
    __syncthreads();
    float sc = scl[row];
    short8 o0v, o1v;
#pragma unroll
    for (int e = 0; e < 8; ++e) {
      o0v[e] = bf16r(t[cg * 16 + e][row] * sc);
      o1v[e] = bf16r(t[cg * 16 + 8 + e][row] * sc);
    }
    size_t base = ((size_t)b * NN + n0 + row) * 256 + c0 + cg * 16;
    *(short8*)&xt[base] = o0v;
    *(short8*)&xt[base + 8] = o1v;
  }
}

// ---------------------------------------------------------------------------
// Kernel 2: fused Q + KV projection MFMA GEMM (one launch).
// grid (16, 12, B): y<4 -> q-proj (o0=y*128, X=fmap_t, out=qb bf16 [b][n][512]);
// y>=4 -> kv-proj (o0=(y-4)*128, X=ctx_t): o0<512 K-part (-2K swizzled tiles
// + fused k2m/mask), else V-part (f16 permuted+swizzled tiles).
// Main loop identical for all blocks; epilogue branch is block-uniform.
// ---------------------------------------------------------------------------
__global__ __launch_bounds__(256) void qkv_gemm_kernel(
    const short* __restrict__ whi, const short* __restrict__ wlo,
    const short* __restrict__ fmap_t, const short* __restrict__ ctx_t,
    short* __restrict__ qb, short* __restrict__ kc, _Float16* __restrict__ vc,
    const int* __restrict__ maskp, float* __restrict__ k2m) {
  const int b = blockIdx.z;
  const int y = blockIdx.y;
  const bool isq = (y < 4);
  const int o0 = (isq ? y : y - 4) * 128;
  const int n0 = blockIdx.x * 128;
  const short* Wh = whi + (isq ? 0 : 131072);
  const short* Wl = wlo + (isq ? 0 : 131072);
  const short* Xt = isq ? fmap_t : ctx_t;

  const int tid = threadIdx.x;
  const int w = tid >> 6, l = tid & 63, quad = l >> 4, l15 = l & 15;
  const int wo = (w >> 1) * 64, wn = (w & 1) * 64;

  __shared__ __align__(16) short Wa[2][128][40];
  __shared__ __align__(16) short Xb[128][40];

  floatx4 acc[4][4];
#pragma unroll
  for (int ot = 0; ot < 4; ++ot)
#pragma unroll
    for (int nt = 0; nt < 4; ++nt)
#pragma unroll
      for (int r = 0; r < 4; ++r) acc[ot][nt][r] = 0.f;

  for (int c0 = 0; c0 < 256; c0 += 32) {
    __syncthreads();
#pragma unroll
    for (int it = 0; it < 2; ++it) {
      int lin = tid + it * 256;
      int row = lin >> 2, sg = (lin & 3) * 8;
      size_t src = (size_t)(o0 + row) * 256 + c0 + sg;
      *(short8*)&Wa[0][row][sg] = *(const short8*)&Wh[src];
      *(short8*)&Wa[1][row][sg] = *(const short8*)&Wl[src];
    }
#pragma unroll
    for (int it = 0; it < 2; ++it) {
      int lin = tid + it * 256;
      int nn = lin >> 2, sg = (lin & 3) * 8;
      *(short8*)&Xb[nn][sg] =
          *(const short8*)&Xt[((size_t)b * 2048 + n0 + nn) * 256 + c0 + sg];
    }
    __syncthreads();

    short8 ah[4], al[4], bx[4];
#pragma unroll
    for (int ot = 0; ot < 4; ++ot) {
      ah[ot] = *(const short8*)&Wa[0][wo + 16 * ot + l15][8 * quad];
      al[ot] = *(const short8*)&Wa[1][wo + 16 * ot + l15][8 * quad];
    }
#pragma unroll
    for (int nt = 0; nt < 4; ++nt)
      bx[nt] = *(const short8*)&Xb[wn + 16 * nt + l15][8 * quad];
#pragma unroll
    for (int ot = 0; ot < 4; ++ot)
#pragma unroll
      for (int nt = 0; nt < 4; ++nt) {
        acc[ot][nt] =
            __builtin_amdgcn_mfma_f32_16x16x32_bf16(al[ot], bx[nt], acc[ot][nt], 0, 0, 0);
        acc[ot][nt] =
            __builtin_amdgcn_mfma_f32_16x16x32_bf16(ah[ot], bx[nt], acc[ot][nt], 0, 0, 0);
      }
  }

  if (isq) {
#pragma unroll
    for (int nt = 0; nt < 4; ++nt) {
      int n = n0 + wn + 16 * nt + l15;
      size_t base = ((size_t)b * 2048 + n) * 512;
#pragma unroll
      for (int ot = 0; ot < 4; ++ot) {
        int o = o0 + wo + 16 * ot + 4 * quad;
        short4v pk;
#pragma unroll
        for (int r = 0; r < 4; ++r) pk[r] = bf16r(acc[ot][nt][r]);
        *(short4v*)&qb[base + o] = pk;
      }
    }
  } else if (o0 < 512) {
    // K part: one head per wave (64 channels), -2 scale, swizzled tiles + k2.
    const int head = (o0 + wo) >> 6;
    const int bh = b * 8 + head;
    float k2p[4] = {0.f, 0.f, 0.f, 0.f};
#pragma unroll
    for (int nt = 0; nt < 4; ++nt) {
      int m = n0 + wn + 16 * nt + l15;
      int chunk = m >> 6, mrow = m & 63;
      size_t tbase = (((size_t)bh * 32 + chunk) * 64 + mrow) * 64;
      int sw = mrow & 7;
#pragma unroll
      for (int ot = 0; ot < 4; ++ot) {
        int d0 = 16 * ot + 4 * quad;
        short4v pk;
#pragma unroll
        for (int r = 0; r < 4; ++r) {
          short pv = bf16r(-2.0f * acc[ot][nt][r]);
          pk[r] = pv;
          float kr = bf2f(pv);
          k2p[nt] += kr * kr;
        }
        *(short4v*)&kc[tbase + (size_t)(((d0 >> 3) ^ sw) << 3) + (d0 & 7)] = pk;
      }
    }
#pragma unroll
    for (int nt = 0; nt < 4; ++nt) {
      float s = k2p[nt];
      s += __shfl_xor(s, 16);
      s += __shfl_xor(s, 32);
      if (quad == 0) {
        int m = n0 + wn + 16 * nt + l15;
        int mv = maskp[b * 2048 + m];
        k2m[(size_t)bh * 2048 + m] = mv ? 0.25f * s : __builtin_inff();
      }
    }
  } else {
    // V part: f16, column permute (PV A-frag order) + group swizzle.
    const int chv = o0 - 512 + wo;  // base channel for this wave (one head)
    const int bh = b * 8 + (chv >> 6);
#pragma unroll
    for (int nt = 0; nt < 4; ++nt) {
      int j = n0 + wn + 16 * nt + l15;
      int chunk = j >> 6, jr = j & 63;
      int jrem = jr & 31;
      int colp = 32 * (jr >> 5) + ((jrem >> 2) & 3) * 8 + (jrem >> 4) * 4 +
                 (jrem & 3);
      size_t cbase = ((size_t)bh * 32 + chunk) * 4096;
#pragma unroll
      for (int ot = 0; ot < 4; ++ot)
#pragma unroll
        for (int r = 0; r < 4; ++r) {
          int drow = (chv + 16 * ot + 4 * quad + r) & 63;
          vc[cbase + drow * 64 + (((colp >> 3) ^ (drow & 7)) << 3) +
             (colp & 7)] = (_Float16)acc[ot][nt][r];
        }
    }
  }
}

// ---------------------------------------------------------------------------
// Kernel 3: L2-distance flash attention, DMA-staged double-buffered j-loop.
// (R10 structure + k2 register prefetch one chunk ahead + shufflevector V.)
// ---------------------------------------------------------------------------
__global__ __launch_bounds__(256, 4) void attn_kernel(
    const short* __restrict__ qb, const short* __restrict__ kc,
    const _Float16* __restrict__ vc, const float* __restrict__ k2m,
    short* __restrict__ attn_t) {
  const int bid = blockIdx.x;
  const int rr = bid & 7, qq = bid >> 3;  // rr ~ XCD
  const int bh = rr * 4 + (qq >> 5);      // 4 bh per XCD
  const int iblk = qq & 31;
  const int h = bh & 7, b = bh >> 3;
  const int i0 = iblk * 64;

  const int tid = threadIdx.x;
  const int w = tid >> 6, l = tid & 63, quad = l >> 4, l15 = l & 15;

  __shared__ __align__(16) short kbuf[2][4096];
  __shared__ __align__(16) short vbuf[2][4096];

  const short* qrow =
      qb + ((size_t)b * 2048 + i0 + 16 * w + l15) * 512 + h * 64;
  const short* kcb = kc + (size_t)bh * 32 * 4096;
  const _Float16* vcb = vc + (size_t)bh * 32 * 4096;
  const float* k2b = k2m + (size_t)bh * 2048;

  // Q^T B-fragments (n=i=l15, k=d=8*quad+jj) + q2 (per-lane scalar)
  short8 qa0 = *(const short8*)&qrow[8 * quad];
  short8 qa1 = *(const short8*)&qrow[32 + 8 * quad];
  float q2p = 0.f;
#pragma unroll
  for (int jj = 0; jj < 8; ++jj) {
    float f0 = bf2f(qa0[jj]), f1 = bf2f(qa1[jj]);
    q2p += f0 * f0 + f1 * f1;
  }
  q2p += __shfl_xor(q2p, 16);
  q2p += __shfl_xor(q2p, 32);
  const float q2c = q2p;

  floatx4 accO[4];
#pragma unroll
  for (int dt = 0; dt < 4; ++dt)
#pragma unroll
    for (int r = 0; r < 4; ++r) accO[dt][r] = 0.f;
  float lsum = 0.f;

  const float C2 = -0.18033688011112042f;  // -0.125 * log2(e)
  const int sx = l15 & 7;                  // swizzle key

  auto stage = [&](int c, int p) {
    const short* ks = kcb + (size_t)c * 4096 + (2 * w) * 512 + l * 8;
    const _Float16* vs = vcb + (size_t)c * 4096 + (2 * w) * 512 + l * 8;
#ifdef HAS_DMA
    __builtin_amdgcn_global_load_lds((gvoid_t*)ks,
                                     (lvoid_t*)&kbuf[p][(2 * w) * 512], 16, 0, 0);
    __builtin_amdgcn_global_load_lds((gvoid_t*)(ks + 512),
                                     (lvoid_t*)&kbuf[p][(2 * w + 1) * 512], 16, 0, 0);
    __builtin_amdgcn_global_load_lds((gvoid_t*)vs,
                                     (lvoid_t*)&vbuf[p][(2 * w) * 512], 16, 0, 0);
    __builtin_amdgcn_global_load_lds((gvoid_t*)(vs + 512),
                                     (lvoid_t*)&vbuf[p][(2 * w + 1) * 512], 16, 0, 0);
#else
    *(short8*)&kbuf[p][(2 * w) * 512 + l * 8] = *(const short8*)ks;
    *(short8*)&kbuf[p][(2 * w + 1) * 512 + l * 8] = *(const short8*)(ks + 512);
    *(half8*)&vbuf[p][(2 * w) * 512 + l * 8] = *(const half8*)vs;
    *(half8*)&vbuf[p][(2 * w + 1) * 512 + l * 8] = *(const half8*)(vs + 512);
#endif
  };

  // prefetch k2 for chunk 0
  float4 k2pref[4];
#pragma unroll
  for (int jt = 0; jt < 4; ++jt)
    k2pref[jt] = *(const float4*)&k2b[16 * jt + 4 * quad];

  stage(0, 0);
  for (int c = 0; c < 32; ++c) {
    __syncthreads();  // drains chunk-c DMA (vmcnt(0) before barrier)
    if (c < 31) stage(c + 1, (c + 1) & 1);
    const int p = c & 1;

    float4 k2cur[4];
#pragma unroll
    for (int jt = 0; jt < 4; ++jt) k2cur[jt] = k2pref[jt];
    if (c < 31) {
#pragma unroll
      for (int jt = 0; jt < 4; ++jt)
        k2pref[jt] = *(const float4*)&k2b[(c + 1) * 64 + 16 * jt + 4 * quad];
    }

    half4 pb[4];
#pragma unroll
    for (int jt = 0; jt < 4; ++jt) {
      const short* kr = &kbuf[p][(16 * jt + l15) * 64];
      short8 k0 = *(const short8*)&kr[(quad ^ sx) << 3];
      short8 k1 = *(const short8*)&kr[((quad + 4) ^ sx) << 3];
      floatx4 a;
      a[0] = q2c; a[1] = q2c; a[2] = q2c; a[3] = q2c;
      a = __builtin_amdgcn_mfma_f32_16x16x32_bf16(k0, qa0, a, 0, 0, 0);
      a = __builtin_amdgcn_mfma_f32_16x16x32_bf16(k1, qa1, a, 0, 0, 0);
      float k2a[4] = {k2cur[jt].x, k2cur[jt].y, k2cur[jt].z, k2cur[jt].w};
#pragma unroll
      for (int r = 0; r < 4; ++r) {
        float d2 = fmaxf(a[r] + k2a[r], 1e-12f);
        float pv = __builtin_amdgcn_exp2f(C2 * __builtin_amdgcn_sqrtf(d2));
        lsum += pv;
        pb[jt][r] = (_Float16)pv;
      }
    }

#pragma unroll
    for (int dt = 0; dt < 4; ++dt) {
      const _Float16* vr = (const _Float16*)&vbuf[p][(16 * dt + l15) * 64];
      half8 h0 = *(const half8*)&vr[(quad ^ sx) << 3];
      half8 h1 = *(const half8*)&vr[((quad + 4) ^ sx) << 3];
      half4 va00 = __builtin_shufflevector(h0, h0, 0, 1, 2, 3);
      half4 va01 = __builtin_shufflevector(h0, h0, 4, 5, 6, 7);
      half4 va10 = __builtin_shufflevector(h1, h1, 0, 1, 2, 3);
      half4 va11 = __builtin_shufflevector(h1, h1, 4, 5, 6, 7);
      accO[dt] = __builtin_amdgcn_mfma_f32_16x16x16f16(va00, pb[0], accO[dt], 0, 0, 0);
      accO[dt] = __builtin_amdgcn_mfma_f32_16x16x16f16(va01, pb[1], accO[dt], 0, 0, 0);
      accO[dt] = __builtin_amdgcn_mfma_f32_16x16x16f16(va10, pb[2], accO[dt], 0, 0, 0);
      accO[dt] = __builtin_amdgcn_mfma_f32_16x16x16f16(va11, pb[3], accO[dt], 0, 0, 0);
    }
  }

  lsum += __shfl_xor(lsum, 16);
  lsum += __shfl_xor(lsum, 32);
  float rl = 1.0f / lsum;
  size_t base = ((size_t)b * 2048 + i0 + 16 * w + l15) * 512 + h * 64;
#pragma unroll
  for (int dt = 0; dt < 4; ++dt)
#pragma unroll
    for (int r = 0; r < 4; ++r)
      attn_t[base + 16 * dt + 4 * quad + r] = bf16r(accO[dt][r] * rl);
}

// ---------------------------------------------------------------------------
// Kernel 4: out-projection MFMA GEMM, 64o x 128n tiles (256 blocks = 1/CU).
// Y fp32 [b][256][2048] = sum_c W'[o][c] * attn_t[b][n][c], C=512.
// 4 waves as 2x2: wave tile 32o x 64n, acc[2][4].
// ---------------------------------------------------------------------------
__global__ __launch_bounds__(256) void outproj_kernel(
    const short* __restrict__ whi, const short* __restrict__ wlo,
    const short* __restrict__ Xt, float* __restrict__ Yf) {
  const int b = blockIdx.z;
  const int n0 = blockIdx.x * 128;
  const int o0 = blockIdx.y * 64;
  const int tid = threadIdx.x;
  const int w = tid >> 6, l = tid & 63, quad = l >> 4, l15 = l & 15;
  const int wo = (w >> 1) * 32, wn = (w & 1) * 64;

  __shared__ __align__(16) short Wa[2][64][40];
  __shared__ __align__(16) short Xb[128][40];

  floatx4 acc[2][4];
#pragma unroll
  for (int ot = 0; ot < 2; ++ot)
#pragma unroll
    for (int nt = 0; nt < 4; ++nt)
#pragma unroll
      for (int r = 0; r < 4; ++r) acc[ot][nt][r] = 0.f;

  for (int c0 = 0; c0 < 512; c0 += 32) {
    __syncthreads();
    {
      int row = tid >> 2, sg = (tid & 3) * 8;  // 64 rows x 32c in one pass
      size_t src = (size_t)(o0 + row) * 512 + c0 + sg;
      *(short8*)&Wa[0][row][sg] = *(const short8*)&whi[src];
      *(short8*)&Wa[1][row][sg] = *(const short8*)&wlo[src];
    }
#pragma unroll
    for (int it = 0; it < 2; ++it) {
      int lin = tid + it * 256;
      int nn = lin >> 2, sg = (lin & 3) * 8;
      *(short8*)&Xb[nn][sg] =
          *(const short8*)&Xt[((size_t)b * 2048 + n0 + nn) * 512 + c0 + sg];
    }
    __syncthreads();

    short8 ah[2], al[2], bx[4];
#pragma unroll
    for (int ot = 0; ot < 2; ++ot) {
      ah[ot] = *(const short8*)&Wa[0][wo + 16 * ot + l15][8 * quad];
      al[ot] = *(const short8*)&Wa[1][wo + 16 * ot + l15][8 * quad];
    }
#pragma unroll
    for (int nt = 0; nt < 4; ++nt)
      bx[nt] = *(const short8*)&Xb[wn + 16 * nt + l15][8 * quad];
#pragma unroll
    for (int ot = 0; ot < 2; ++ot)
#pragma unroll
      for (int nt = 0; nt < 4; ++nt) {
        acc[ot][nt] =
            __builtin_amdgcn_mfma_f32_16x16x32_bf16(al[ot], bx[nt], acc[ot][nt], 0, 0, 0);
        acc[ot][nt] =
            __builtin_amdgcn_mfma_f32_16x16x32_bf16(ah[ot], bx[nt], acc[ot][nt], 0, 0, 0);
      }
  }

#pragma unroll
  for (int ot = 0; ot < 2; ++ot)
#pragma unroll
    for (int r = 0; r < 4; ++r) {
      int o = o0 + wo + 16 * ot + 4 * quad + r;
#pragma unroll
      for (int nt = 0; nt < 4; ++nt)
        Yf[((size_t)b * 256 + o) * 2048 + n0 + wn + 16 * nt + l15] =
            acc[ot][nt][r];
    }
}

// ---------------------------------------------------------------------------
extern "C" void kernel_launch(void* const* d_in, const int* in_sizes, int n_in,
                              void* d_out, int out_size, void* d_ws,
                              size_t ws_size, hipStream_t stream) {
  const float* fmap = (const float*)d_in[0];
  const float* context = (const float*)d_in[1];
  const int* mask = (const int*)d_in[2];
  const float* gamma = (const float*)d_in[3];
  const float* gamma_ctx = (const float*)d_in[4];
  const float* Wq = (const float*)d_in[5];
  const float* Wkv = (const float*)d_in[6];
  const float* Wout = (const float*)d_in[7];
  float* out = (float*)d_out;

  char* ws = (char*)d_ws;
  short* fmap_t = (short*)ws;                 // 4 MB
  short* ctx_t = fmap_t + 2097152;            // 4 MB
  short* qb = ctx_t + 2097152;                // 8 MB
  short* kc = qb + 4194304;                   // 8 MB (-2K, swizzled tiles)
  _Float16* vc = (_Float16*)(kc + 4194304);   // 8 MB (f16, permuted tiles)
  short* attn_t = (short*)(vc + 4194304);     // 8 MB
  float* k2m = (float*)(attn_t + 4194304);    // 256 KB
  short* whi = (short*)(k2m + 65536);         // 1 MB
  short* wlo = whi + 524288;                  // 1 MB

  dim3 blk64x4(64, 4);
  wsplit_kernel<<<dim3(256, 3), 256, 0, stream>>>(Wq, Wkv, Wout, gamma,
                                                  gamma_ctx, whi, wlo);
  colnorm_t_kernel<<<dim3(32, B_, 2), blk64x4, 0, stream>>>(
      fmap, context, fmap_t, ctx_t, N_);
  qkv_gemm_kernel<<<dim3(16, 12, B_), 256, 0, stream>>>(
      whi, wlo, fmap_t, ctx_t, qb, kc, vc, mask, k2m);
  attn_kernel<<<dim3(1024), 256, 0, stream>>>(qb, kc, vc, k2m, attn_t);
  outproj_kernel<<<dim3(16, 4, B_), 256, 0, stream>>>(whi + 393216,
                                                      wlo + 393216, attn_t,
                                                      out);
}